// Round 2
// baseline (9366.010 us; speedup 1.0000x reference)
//
#include <hip/hip_runtime.h>
#include <stdint.h>

#define T_IN  128
#define T_OUT 50

typedef __bf16 bf16x8_t __attribute__((ext_vector_type(8)));
typedef float  f32x4_t  __attribute__((ext_vector_type(4)));

#define HROW_BYTES 176
#define HBUF_WAVE  (16 * HROW_BYTES)   // 2816 B per wave

__device__ __forceinline__ float rcp_f(float x) { return __builtin_amdgcn_rcpf(x); }
__device__ __forceinline__ uint32_t pk(__bf16 a, __bf16 b) {
    return (uint32_t)__builtin_bit_cast(uint16_t, a) |
           ((uint32_t)__builtin_bit_cast(uint16_t, b) << 16);
}

// MFMA layout (verified m89/m91):
//   A  : A[m = lane&15][k = (lane>>4)*8 + j]
//   B  : B[k = (lane>>4)*8 + j][n = lane&15]
//   C/D: col = lane&15, row = (lane>>4)*4 + reg
// k-permutation pi(p) = (p>>2) + 16*(p&3) applied to both Whh k-columns and h
// stores (slabs 0/1 only; slab 2 = [x0, x1, 1, 0...] uses identity layout).

__global__ __launch_bounds__(1024, 4) void seq2seq_lstm(
    const float* __restrict__ in_seq,
    const float* __restrict__ WihE, const float* __restrict__ WhhE,
    const float* __restrict__ bihE, const float* __restrict__ bhhE,
    const float* __restrict__ WihD, const float* __restrict__ WhhD,
    const float* __restrict__ bihD, const float* __restrict__ bhhD,
    const float* __restrict__ Wfc,  const float* __restrict__ bfc,
    float* __restrict__ out)
{
    // 48 frags x 1024 B: fg 0..31 = Whh slabs (tile*2+kf), fg 32..47 = slab2
    __shared__ __align__(16) uint8_t sFrag[49152];
    __shared__ __align__(16) uint8_t sHbuf[16 * HBUF_WAVE];   // 45056
    __shared__ __align__(16) uint8_t sXbuf[16 * 2048];        // 32768
    // total 126976 B -> 1 block/CU, 16 waves/CU

    const int tid  = threadIdx.x;
    const int lane = tid & 63;
    const int wave = tid >> 6;
    const int c    = lane & 15;
    const int q    = lane >> 4;

    auto stage_frags = [&](const float* Whh, const float* Wih,
                           const float* bih, const float* bhh) {
        #pragma unroll 1
        for (int it = 0; it < 3; ++it) {
            int idx = it * 1024 + tid;      // 0..3071 = frag(0..47) x lane(0..63)
            int ln  = idx & 63;
            int fg  = idx >> 6;
            int n   = ln & 15;
            int qq  = ln >> 4;
            uint32_t wv[4] = {0u, 0u, 0u, 0u};
            if (fg < 32) {
                int kf = fg & 1;
                int t  = fg >> 1;
                const float* wr = Whh + (t * 16 + n) * 64;
                #pragma unroll
                for (int jj = 0; jj < 4; ++jj) {
                    int p0 = kf * 32 + qq * 8 + 2 * jj;
                    int p1 = p0 + 1;
                    int k0 = (p0 >> 2) + 16 * (p0 & 3);
                    int k1 = (p1 >> 2) + 16 * (p1 & 3);
                    wv[jj] = pk((__bf16)wr[k0], (__bf16)wr[k1]);
                }
            } else if (qq == 0) {
                int n2 = (fg - 32) * 16 + n;
                wv[0] = pk((__bf16)Wih[n2 * 2 + 0], (__bf16)Wih[n2 * 2 + 1]);
                wv[1] = pk((__bf16)(bih[n2] + bhh[n2]), (__bf16)0.0f);
            }
            uint32_t* d = (uint32_t*)(sFrag + fg * 1024 + ln * 16);
            d[0] = wv[0]; d[1] = wv[1]; d[2] = wv[2]; d[3] = wv[3];
        }
    };

    stage_frags(WhhE, WihE, bihE, bhhE);
    for (int i = tid; i < (16 * HBUF_WAVE) / 4; i += 1024)
        ((uint32_t*)sHbuf)[i] = 0u;
    __syncthreads();

    uint8_t* hb  = sHbuf + wave * HBUF_WAVE;
    uint8_t* sXw = sXbuf + wave * 2048;
    const int rowBase = blockIdx.x * 256 + wave * 16;

    f32x4_t cst[4], hst[4];
    #pragma unroll
    for (int tc = 0; tc < 4; ++tc) cst[tc] = (f32x4_t){0.f, 0.f, 0.f, 0.f};

    // one LSTM step; xpack = bf16x2 {x0,x1} for batch-row c (used by q==0 lanes)
    auto lstm_step = [&](uint32_t xpack) {
        const uint8_t* hrow = hb + c * HROW_BYTES;
        bf16x8_t a0 = *(const bf16x8_t*)(hrow + q * 16);
        bf16x8_t a1 = *(const bf16x8_t*)(hrow + 64 + q * 16);
        union { bf16x8_t v; uint32_t u[4]; } ua;
        ua.u[0] = (q == 0) ? xpack : 0u;
        ua.u[1] = (q == 0) ? 0x00003F80u : 0u;   // bf16 1.0 at k=66
        ua.u[2] = 0u; ua.u[3] = 0u;
        bf16x8_t a2 = ua.v;

        #pragma unroll
        for (int tc = 0; tc < 4; ++tc) {
            f32x4_t acc[4];   // gi: 0=i,1=f,2=g,3=o  (tile = tc + 4*gi)
            #pragma unroll
            for (int gi = 0; gi < 4; ++gi) {
                int t = tc + gi * 4;
                bf16x8_t b0 = *(const bf16x8_t*)(sFrag + (2 * t) * 1024 + lane * 16);
                bf16x8_t b1 = *(const bf16x8_t*)(sFrag + (2 * t + 1) * 1024 + lane * 16);
                bf16x8_t b2 = *(const bf16x8_t*)(sFrag + 32768 + t * 1024 + lane * 16);
                f32x4_t z = {0.f, 0.f, 0.f, 0.f};
                f32x4_t a = __builtin_amdgcn_mfma_f32_16x16x32_bf16(a0, b0, z, 0, 0, 0);
                a = __builtin_amdgcn_mfma_f32_16x16x32_bf16(a1, b1, a, 0, 0, 0);
                acc[gi] = __builtin_amdgcn_mfma_f32_16x16x32_bf16(a2, b2, a, 0, 0, 0);
            }
            float ec[4], ogs[4];
            #pragma unroll
            for (int r = 0; r < 4; ++r) {
                float ea  = __expf(-acc[0][r]);
                float efv = __expf(-acc[1][r]);
                float egv = __expf(-2.f * acc[2][r]);
                float eov = __expf(-acc[3][r]);
                float pa = 1.f + ea, pfv = 1.f + efv, pg = 1.f + egv, po = 1.f + eov;
                float A  = pa * pg, Bq = pfv * po;
                float rr = rcp_f(A * Bq);
                float rA = rr * A;                 // = 1/(pf*po)
                float igp = (1.f - egv) * rr * Bq; // = i*g
                float fgt = rA * po;               // = sigmoid(f)
                float ogt = rA * pfv;              // = sigmoid(o)
                float cn  = fgt * cst[tc][r] + igp;
                cst[tc][r] = cn;
                float cc = fminf(fmaxf(cn, -15.f), 15.f);
                ec[r]  = __expf(-2.f * cc);
                ogs[r] = ogt;
            }
            #pragma unroll
            for (int rp = 0; rp < 2; ++rp) {
                float e0 = ec[2 * rp], e1 = ec[2 * rp + 1];
                float C0 = 1.f + e0, C1 = 1.f + e1;
                float rr2 = rcp_f(C0 * C1);
                hst[tc][2 * rp]     = ogs[2 * rp]     * (1.f - e0) * rr2 * C1;
                hst[tc][2 * rp + 1] = ogs[2 * rp + 1] * (1.f - e1) * rr2 * C0;
            }
        }
        #pragma unroll
        for (int r = 0; r < 4; ++r) {
            uint2 u;
            u.x = pk((__bf16)hst[0][r], (__bf16)hst[1][r]);
            u.y = pk((__bf16)hst[2][r], (__bf16)hst[3][r]);
            *(uint2*)(hb + (4 * q + r) * HROW_BYTES + c * 8) = u;
        }
    };

    // ================= encoder =================
    // staging: lane covers row (lane>>2), steps (lane&3)*4..+3 of each 16-step chunk
    const float* gsrc = in_seq + (size_t)(rowBase + (lane >> 2)) * (T_IN * 2)
                               + (lane & 3) * 8;
    float4 pf0, pf1;
    pf0 = *(const float4*)gsrc;
    pf1 = *(const float4*)(gsrc + 4);

    #pragma unroll 1
    for (int t = 0; t < T_IN; ++t) {
        if ((t & 15) == 0) {
            // write prefetched chunk (transposed: [t][row], 128 B per step)
            int row = lane >> 2, s0 = (lane & 3) * 4;
            *(float2*)(sXw + (s0 + 0) * 128 + row * 8) = make_float2(pf0.x, pf0.y);
            *(float2*)(sXw + (s0 + 1) * 128 + row * 8) = make_float2(pf0.z, pf0.w);
            *(float2*)(sXw + (s0 + 2) * 128 + row * 8) = make_float2(pf1.x, pf1.y);
            *(float2*)(sXw + (s0 + 3) * 128 + row * 8) = make_float2(pf1.z, pf1.w);
            if (t < T_IN - 16) {
                const float* p = gsrc + ((t >> 4) + 1) * 32;
                pf0 = *(const float4*)p;
                pf1 = *(const float4*)(p + 4);
            }
        }
        float2 xv = *(const float2*)(sXw + (t & 15) * 128 + c * 8);
        lstm_step(pk((__bf16)xv.x, (__bf16)xv.y));
    }

    // ============ switch to decoder weights ============
    __syncthreads();
    stage_frags(WhhD, WihD, bihD, bhhD);
    __syncthreads();

    float wf0[4], wf1[4];
    #pragma unroll
    for (int tc = 0; tc < 4; ++tc) {
        wf0[tc] = Wfc[c + 16 * tc];
        wf1[tc] = Wfc[64 + c + 16 * tc];
    }
    const float bfc0 = bfc[0], bfc1 = bfc[1];

    // dec_in0 = input_seq[:, -1]: chunk 7 / local step 15 still resident in sXw
    float2 x127 = *(const float2*)(sXw + 15 * 128 + c * 8);
    uint32_t xpack = pk((__bf16)x127.x, (__bf16)x127.y);

    // ================= decoder =================
    #pragma unroll 1
    for (int td = 0; td < T_OUT; ++td) {
        lstm_step(xpack);
        float s0[4], s1[4];
        #pragma unroll
        for (int r = 0; r < 4; ++r) {
            s0[r] = hst[0][r]*wf0[0] + hst[1][r]*wf0[1] + hst[2][r]*wf0[2] + hst[3][r]*wf0[3];
            s1[r] = hst[0][r]*wf1[0] + hst[1][r]*wf1[1] + hst[2][r]*wf1[2] + hst[3][r]*wf1[3];
        }
        #pragma unroll
        for (int m = 1; m <= 8; m <<= 1) {
            #pragma unroll
            for (int r = 0; r < 4; ++r) {
                s0[r] += __shfl_xor(s0[r], m, 64);
                s1[r] += __shfl_xor(s1[r], m, 64);
            }
        }
        float x0n[4], x1n[4];
        #pragma unroll
        for (int r = 0; r < 4; ++r) {
            x0n[r] = rcp_f(1.f + __expf(-(s0[r] + bfc0)));
            x1n[r] = rcp_f(1.f + __expf(-(s1[r] + bfc1)));
        }
        if (c == 0) {
            #pragma unroll
            for (int r = 0; r < 4; ++r) {
                *(float2*)(out + ((size_t)(rowBase + 4 * q + r) * T_OUT + td) * 2)
                    = make_float2(x0n[r], x1n[r]);
            }
        }
        // route x(row c) to this lane for next step's a2: row c lives in
        // register (c&3) of lanes with q' = c>>2
        float t0[4], t1[4];
        #pragma unroll
        for (int r = 0; r < 4; ++r) {
            t0[r] = __shfl(x0n[r], (c >> 2) << 4, 64);
            t1[r] = __shfl(x1n[r], (c >> 2) << 4, 64);
        }
        float xa = (c & 2) ? ((c & 1) ? t0[3] : t0[2]) : ((c & 1) ? t0[1] : t0[0]);
        float xb = (c & 2) ? ((c & 1) ? t1[3] : t1[2]) : ((c & 1) ? t1[1] : t1[0]);
        xpack = pk((__bf16)xa, (__bf16)xb);
    }
}

extern "C" void kernel_launch(void* const* d_in, const int* in_sizes, int n_in,
                              void* d_out, int out_size, void* d_ws, size_t ws_size,
                              hipStream_t stream) {
    const float* in_seq = (const float*)d_in[0];
    const float* WihE = (const float*)d_in[1];
    const float* WhhE = (const float*)d_in[2];
    const float* bihE = (const float*)d_in[3];
    const float* bhhE = (const float*)d_in[4];
    const float* WihD = (const float*)d_in[5];
    const float* WhhD = (const float*)d_in[6];
    const float* bihD = (const float*)d_in[7];
    const float* bihD2 = (const float*)d_in[8];
    const float* Wfc  = (const float*)d_in[9];
    const float* bfcp = (const float*)d_in[10];
    float* out = (float*)d_out;

    const int B = in_sizes[0] / (T_IN * 2);   // 131072
    dim3 grid(B / 256), block(1024);          // 256 rows/block (16 waves x 16)
    hipLaunchKernelGGL(seq2seq_lstm, grid, block, 0, stream,
                       in_seq, WihE, WhhE, bihE, bhhE,
                       WihD, WhhD, bihD, bihD2, Wfc, bfcp, out);
}

// Round 3
// 8744.950 us; speedup vs baseline: 1.0710x; 1.0710x over previous
//
#include <hip/hip_runtime.h>
#include <stdint.h>

#define T_IN  128
#define T_OUT 50
#define NW    8          // waves per block (512 threads)

typedef __bf16 bf16x8_t __attribute__((ext_vector_type(8)));
typedef float  f32x4_t  __attribute__((ext_vector_type(4)));

#define HROW_BYTES 176
#define HBUF_WAVE  (16 * HROW_BYTES)   // 2816 B per wave

__device__ __forceinline__ float rcp_f(float x) { return __builtin_amdgcn_rcpf(x); }
__device__ __forceinline__ uint32_t pk(__bf16 a, __bf16 b) {
    return (uint32_t)__builtin_bit_cast(uint16_t, a) |
           ((uint32_t)__builtin_bit_cast(uint16_t, b) << 16);
}

// MFMA layout (verified m89/m91):
//   A  : A[m = lane&15][k = (lane>>4)*8 + j]
//   B  : B[k = (lane>>4)*8 + j][n = lane&15]
//   C/D: col = lane&15, row = (lane>>4)*4 + reg
// k-permutation pi(p) = (p>>2) + 16*(p&3) applied to both Whh k-columns and h
// stores. Slab2 (K=32: [x0,x1,1,0...]) uses identity layout; its B-fragment is
// nonzero only for q==0 lanes (k<8), so it's stored compactly: 8 B per (t,n).

__global__ __launch_bounds__(512, 4) void seq2seq_lstm(
    const float* __restrict__ in_seq,
    const float* __restrict__ WihE, const float* __restrict__ WhhE,
    const float* __restrict__ bihE, const float* __restrict__ bhhE,
    const float* __restrict__ WihD, const float* __restrict__ WhhD,
    const float* __restrict__ bihD, const float* __restrict__ bhhD,
    const float* __restrict__ Wfc,  const float* __restrict__ bfc,
    float* __restrict__ out)
{
    __shared__ __align__(16) uint8_t sFrag[32768];        // 32 Whh B-frags
    __shared__ __align__(16) uint8_t sB2[2048];           // compact slab2: [t][n] uint2
    __shared__ __align__(16) uint8_t sHbuf[NW * HBUF_WAVE]; // 22528
    __shared__ __align__(16) uint8_t sXbuf[NW * 2048];      // 16384
    // total 73728 B -> 2 blocks/CU, 16 waves/CU; VGPR cap 128 (4 waves/EU)

    const int tid  = threadIdx.x;
    const int lane = tid & 63;
    const int wave = tid >> 6;
    const int c    = lane & 15;
    const int q    = lane >> 4;

    auto stage_frags = [&](const float* Whh, const float* Wih,
                           const float* bih, const float* bhh) {
        #pragma unroll 1
        for (int it = 0; it < 4; ++it) {
            int idx = it * 512 + tid;   // 0..2047 = frag(0..31) x lane(0..63)
            int ln  = idx & 63;
            int fg  = idx >> 6;         // fg = tile*2 + kf
            int kf  = fg & 1;
            int t   = fg >> 1;
            int n   = ln & 15;
            int qq  = ln >> 4;
            const float* wr = Whh + (t * 16 + n) * 64;
            uint32_t wv[4];
            #pragma unroll
            for (int jj = 0; jj < 4; ++jj) {
                int p0 = kf * 32 + qq * 8 + 2 * jj;
                int p1 = p0 + 1;
                int k0 = (p0 >> 2) + 16 * (p0 & 3);
                int k1 = (p1 >> 2) + 16 * (p1 & 3);
                wv[jj] = pk((__bf16)wr[k0], (__bf16)wr[k1]);
            }
            uint32_t* d = (uint32_t*)(sFrag + fg * 1024 + ln * 16);
            d[0] = wv[0]; d[1] = wv[1]; d[2] = wv[2]; d[3] = wv[3];
        }
        if (tid < 256) {
            int t = tid >> 4, n = tid & 15;
            int n2 = t * 16 + n;
            uint2 u;
            u.x = pk((__bf16)Wih[n2 * 2 + 0], (__bf16)Wih[n2 * 2 + 1]);
            u.y = pk((__bf16)(bih[n2] + bhh[n2]), (__bf16)0.0f);
            *(uint2*)(sB2 + t * 128 + n * 8) = u;
        }
    };

    stage_frags(WhhE, WihE, bihE, bhhE);
    for (int i = tid; i < (NW * HBUF_WAVE) / 4; i += 512)
        ((uint32_t*)sHbuf)[i] = 0u;
    __syncthreads();
    // ---- no barriers inside the time loops: each wave owns its 16 rows ----

    uint8_t* hb  = sHbuf + wave * HBUF_WAVE;
    uint8_t* sXw = sXbuf + wave * 2048;
    const int rowBase = blockIdx.x * (NW * 16) + wave * 16;

    f32x4_t cst[4], hst[4];
    #pragma unroll
    for (int tc = 0; tc < 4; ++tc) cst[tc] = (f32x4_t){0.f, 0.f, 0.f, 0.f};

    auto lstm_step = [&](uint32_t xpack) {
        const uint8_t* hrow = hb + c * HROW_BYTES;
        bf16x8_t a0 = *(const bf16x8_t*)(hrow + q * 16);
        bf16x8_t a1 = *(const bf16x8_t*)(hrow + 64 + q * 16);
        union { bf16x8_t v; uint32_t u[4]; } ua;
        ua.u[0] = (q == 0) ? xpack : 0u;
        ua.u[1] = (q == 0) ? 0x00003F80u : 0u;   // bf16 1.0 at k=2
        ua.u[2] = 0u; ua.u[3] = 0u;
        bf16x8_t a2 = ua.v;

        #pragma unroll
        for (int tc = 0; tc < 4; ++tc) {
            f32x4_t acc[4];   // gi: 0=i,1=f,2=g,3=o  (tile = tc + 4*gi)
            #pragma unroll
            for (int gi = 0; gi < 4; ++gi) {
                int t = tc + gi * 4;
                bf16x8_t b0 = *(const bf16x8_t*)(sFrag + (2 * t) * 1024 + lane * 16);
                bf16x8_t b1 = *(const bf16x8_t*)(sFrag + (2 * t + 1) * 1024 + lane * 16);
                uint2 w2 = *(const uint2*)(sB2 + t * 128 + c * 8);
                union { bf16x8_t v; uint32_t u[4]; } ub;
                ub.u[0] = (q == 0) ? w2.x : 0u;
                ub.u[1] = (q == 0) ? w2.y : 0u;
                ub.u[2] = 0u; ub.u[3] = 0u;
                f32x4_t z = {0.f, 0.f, 0.f, 0.f};
                f32x4_t a = __builtin_amdgcn_mfma_f32_16x16x32_bf16(a0, b0, z, 0, 0, 0);
                a = __builtin_amdgcn_mfma_f32_16x16x32_bf16(a1, b1, a, 0, 0, 0);
                acc[gi] = __builtin_amdgcn_mfma_f32_16x16x32_bf16(a2, ub.v, a, 0, 0, 0);
            }
            float ec[4], ogs[4];
            #pragma unroll
            for (int r = 0; r < 4; ++r) {
                float ea  = __expf(-acc[0][r]);
                float efv = __expf(-acc[1][r]);
                float egv = __expf(-2.f * acc[2][r]);
                float eov = __expf(-acc[3][r]);
                float pa = 1.f + ea, pfv = 1.f + efv, pg = 1.f + egv, po = 1.f + eov;
                float A  = pa * pg, Bq = pfv * po;
                float rr = rcp_f(A * Bq);
                float rA = rr * A;                 // = 1/(pf*po)
                float igp = (1.f - egv) * rr * Bq; // = i*g
                float fgt = rA * po;               // = sigmoid(f)
                float ogt = rA * pfv;              // = sigmoid(o)
                float cn  = fgt * cst[tc][r] + igp;
                cst[tc][r] = cn;
                float cc = fminf(fmaxf(cn, -15.f), 15.f);
                ec[r]  = __expf(-2.f * cc);
                ogs[r] = ogt;
            }
            #pragma unroll
            for (int rp = 0; rp < 2; ++rp) {
                float e0 = ec[2 * rp], e1 = ec[2 * rp + 1];
                float C0 = 1.f + e0, C1 = 1.f + e1;
                float rr2 = rcp_f(C0 * C1);
                hst[tc][2 * rp]     = ogs[2 * rp]     * (1.f - e0) * rr2 * C1;
                hst[tc][2 * rp + 1] = ogs[2 * rp + 1] * (1.f - e1) * rr2 * C0;
            }
        }
        #pragma unroll
        for (int r = 0; r < 4; ++r) {
            uint2 u;
            u.x = pk((__bf16)hst[0][r], (__bf16)hst[1][r]);
            u.y = pk((__bf16)hst[2][r], (__bf16)hst[3][r]);
            *(uint2*)(hb + (4 * q + r) * HROW_BYTES + c * 8) = u;
        }
    };

    // ================= encoder =================
    const float* gsrc = in_seq + (size_t)(rowBase + (lane >> 2)) * (T_IN * 2)
                               + (lane & 3) * 8;
    float4 pf0 = *(const float4*)gsrc;
    float4 pf1 = *(const float4*)(gsrc + 4);

    #pragma unroll 1
    for (int t = 0; t < T_IN; ++t) {
        if ((t & 15) == 0) {
            int row = lane >> 2, s0 = (lane & 3) * 4;
            *(float2*)(sXw + (s0 + 0) * 128 + row * 8) = make_float2(pf0.x, pf0.y);
            *(float2*)(sXw + (s0 + 1) * 128 + row * 8) = make_float2(pf0.z, pf0.w);
            *(float2*)(sXw + (s0 + 2) * 128 + row * 8) = make_float2(pf1.x, pf1.y);
            *(float2*)(sXw + (s0 + 3) * 128 + row * 8) = make_float2(pf1.z, pf1.w);
            if (t < T_IN - 16) {
                const float* p = gsrc + ((t >> 4) + 1) * 32;
                pf0 = *(const float4*)p;
                pf1 = *(const float4*)(p + 4);
            }
        }
        float2 xv = *(const float2*)(sXw + (t & 15) * 128 + c * 8);
        lstm_step(pk((__bf16)xv.x, (__bf16)xv.y));
    }

    // ============ switch to decoder weights ============
    __syncthreads();
    stage_frags(WhhD, WihD, bihD, bhhD);
    __syncthreads();

    float wf0[4], wf1[4];
    #pragma unroll
    for (int tc = 0; tc < 4; ++tc) {
        wf0[tc] = Wfc[c + 16 * tc];
        wf1[tc] = Wfc[64 + c + 16 * tc];
    }
    const float bfc0 = bfc[0], bfc1 = bfc[1];

    float2 x127 = *(const float2*)(sXw + 15 * 128 + c * 8);   // input_seq[:, -1]
    uint32_t xpack = pk((__bf16)x127.x, (__bf16)x127.y);

    // ================= decoder =================
    #pragma unroll 1
    for (int td = 0; td < T_OUT; ++td) {
        lstm_step(xpack);
        float s0[4], s1[4];
        #pragma unroll
        for (int r = 0; r < 4; ++r) {
            s0[r] = hst[0][r]*wf0[0] + hst[1][r]*wf0[1] + hst[2][r]*wf0[2] + hst[3][r]*wf0[3];
            s1[r] = hst[0][r]*wf1[0] + hst[1][r]*wf1[1] + hst[2][r]*wf1[2] + hst[3][r]*wf1[3];
        }
        #pragma unroll
        for (int m = 1; m <= 8; m <<= 1) {
            #pragma unroll
            for (int r = 0; r < 4; ++r) {
                s0[r] += __shfl_xor(s0[r], m, 64);
                s1[r] += __shfl_xor(s1[r], m, 64);
            }
        }
        float x0n[4], x1n[4];
        #pragma unroll
        for (int r = 0; r < 4; ++r) {
            x0n[r] = rcp_f(1.f + __expf(-(s0[r] + bfc0)));
            x1n[r] = rcp_f(1.f + __expf(-(s1[r] + bfc1)));
        }
        if (c == 0) {
            #pragma unroll
            for (int r = 0; r < 4; ++r) {
                *(float2*)(out + ((size_t)(rowBase + 4 * q + r) * T_OUT + td) * 2)
                    = make_float2(x0n[r], x1n[r]);
            }
        }
        // route x(row c) to this lane: row c lives in register (c&3) of lanes
        // with quad c>>2 (lane (c>>2)*16 holds it after the butterfly)
        float t0[4], t1[4];
        #pragma unroll
        for (int r = 0; r < 4; ++r) {
            t0[r] = __shfl(x0n[r], (c >> 2) << 4, 64);
            t1[r] = __shfl(x1n[r], (c >> 2) << 4, 64);
        }
        float xa = (c & 2) ? ((c & 1) ? t0[3] : t0[2]) : ((c & 1) ? t0[1] : t0[0]);
        float xb = (c & 2) ? ((c & 1) ? t1[3] : t1[2]) : ((c & 1) ? t1[1] : t1[0]);
        xpack = pk((__bf16)xa, (__bf16)xb);
    }
}

extern "C" void kernel_launch(void* const* d_in, const int* in_sizes, int n_in,
                              void* d_out, int out_size, void* d_ws, size_t ws_size,
                              hipStream_t stream) {
    const float* in_seq = (const float*)d_in[0];
    const float* WihE = (const float*)d_in[1];
    const float* WhhE = (const float*)d_in[2];
    const float* bihE = (const float*)d_in[3];
    const float* bhhE = (const float*)d_in[4];
    const float* WihD = (const float*)d_in[5];
    const float* WhhD = (const float*)d_in[6];
    const float* bihD = (const float*)d_in[7];
    const float* bhhD = (const float*)d_in[8];
    const float* Wfc  = (const float*)d_in[9];
    const float* bfcp = (const float*)d_in[10];
    float* out = (float*)d_out;

    const int B = in_sizes[0] / (T_IN * 2);   // 131072
    dim3 grid(B / (NW * 16)), block(NW * 64); // 128 rows/block (8 waves x 16)
    hipLaunchKernelGGL(seq2seq_lstm, grid, block, 0, stream,
                       in_seq, WihE, WhhE, bihE, bhhE,
                       WihD, WhhD, bihD, bhhD, Wfc, bfcp, out);
}

// Round 4
// 3226.218 us; speedup vs baseline: 2.9031x; 2.7106x over previous
//
#include <hip/hip_runtime.h>
#include <stdint.h>

#define T_IN  128
#define T_OUT 50
#define NW    4          // waves per block (256 threads)

typedef __bf16 bf16x8_t __attribute__((ext_vector_type(8)));
typedef float  f32x4_t  __attribute__((ext_vector_type(4)));

#define HROW_BYTES 176
#define HBUF_WAVE  (16 * HROW_BYTES)   // 2816 B per wave

__device__ __forceinline__ float rcp_f(float x) { return __builtin_amdgcn_rcpf(x); }
__device__ __forceinline__ uint32_t pk(__bf16 a, __bf16 b) {
    return (uint32_t)__builtin_bit_cast(uint16_t, a) |
           ((uint32_t)__builtin_bit_cast(uint16_t, b) << 16);
}

// MFMA layout (verified m89/m91):
//   A  : A[m = lane&15][k = (lane>>4)*8 + j]
//   B  : B[k = (lane>>4)*8 + j][n = lane&15]
//   C/D: col = lane&15, row = (lane>>4)*4 + reg
// k-permutation pi(p) = (p>>2) + 16*(p&3) applied to both Whh k-columns and h
// stores. Slab2 (K=32: [x0,x1,1,0...]) uses identity layout; B rows k>=3 are
// zero, so its per-lane fragment is zero for q>0 lanes -> stored zero-PADDED
// in LDS (512 B/tile) for a select-free ds_read_b64.
//
// REGISTER BUDGET NOTE (rounds 2/3 post-mortem): demand is ~190 total
// (arch+acc, unified file). __launch_bounds__ caps of 128 caused 85
// spill-reloads/step = 31 GB scratch traffic = the whole runtime.
// (256,2) -> cap 256: guaranteed no spill (proven in round 1).

__global__ __launch_bounds__(256, 2) void seq2seq_lstm(
    const float* __restrict__ in_seq,
    const float* __restrict__ WihE, const float* __restrict__ WhhE,
    const float* __restrict__ bihE, const float* __restrict__ bhhE,
    const float* __restrict__ WihD, const float* __restrict__ WhhD,
    const float* __restrict__ bihD, const float* __restrict__ bhhD,
    const float* __restrict__ Wfc,  const float* __restrict__ bfc,
    float* __restrict__ out)
{
    __shared__ __align__(16) uint8_t sFrag[32768];          // 32 Whh B-frags
    __shared__ __align__(16) uint8_t sB2[8192];             // slab2, zero-padded
    __shared__ __align__(16) uint8_t sHbuf[NW * HBUF_WAVE]; // 11264
    __shared__ __align__(16) uint8_t sXbuf[NW * 2048];      // 8192
    // total 60416 B -> 2 blocks/CU (8 waves/CU)

    const int tid  = threadIdx.x;
    const int lane = tid & 63;
    const int wave = tid >> 6;
    const int c    = lane & 15;
    const int q    = lane >> 4;

    auto stage_frags = [&](const float* Whh, const float* Wih,
                           const float* bih, const float* bhh) {
        #pragma unroll 1
        for (int it = 0; it < 8; ++it) {
            int idx = it * 256 + tid;   // 0..2047 = frag(0..31) x lane(0..63)
            int ln  = idx & 63;
            int fg  = idx >> 6;         // fg = tile*2 + kf
            int kf  = fg & 1;
            int t   = fg >> 1;
            int n   = ln & 15;
            int qq  = ln >> 4;
            const float* wr = Whh + (t * 16 + n) * 64;
            uint32_t wv[4];
            #pragma unroll
            for (int jj = 0; jj < 4; ++jj) {
                int p0 = kf * 32 + qq * 8 + 2 * jj;
                int p1 = p0 + 1;
                int k0 = (p0 >> 2) + 16 * (p0 & 3);
                int k1 = (p1 >> 2) + 16 * (p1 & 3);
                wv[jj] = pk((__bf16)wr[k0], (__bf16)wr[k1]);
            }
            uint32_t* d = (uint32_t*)(sFrag + fg * 1024 + ln * 16);
            d[0] = wv[0]; d[1] = wv[1]; d[2] = wv[2]; d[3] = wv[3];
        }
        // slab2: tile t occupies 512 B; lane ln reads 8 B at ln*8.
        // Nonzero only for ln<16 (q==0 -> k=0..7): {pk(Wih row), pk(bias,0)}.
        #pragma unroll 1
        for (int it = 0; it < 4; ++it) {
            int idx = it * 256 + tid;   // 0..1023 = tile(0..15) x lane(0..63)
            int ln  = idx & 63;
            int t   = idx >> 6;
            uint2 u = make_uint2(0u, 0u);
            if (ln < 16) {
                int n2 = t * 16 + ln;
                u.x = pk((__bf16)Wih[n2 * 2 + 0], (__bf16)Wih[n2 * 2 + 1]);
                u.y = pk((__bf16)(bih[n2] + bhh[n2]), (__bf16)0.0f);
            }
            *(uint2*)(sB2 + t * 512 + ln * 8) = u;
        }
    };

    stage_frags(WhhE, WihE, bihE, bhhE);
    for (int i = tid; i < (NW * HBUF_WAVE) / 4; i += 256)
        ((uint32_t*)sHbuf)[i] = 0u;
    __syncthreads();
    // ---- no barriers inside the time loops: each wave owns its 16 rows ----

    uint8_t* hb  = sHbuf + wave * HBUF_WAVE;
    uint8_t* sXw = sXbuf + wave * 2048;
    const int rowBase = blockIdx.x * (NW * 16) + wave * 16;

    f32x4_t cst[4], hst[4];
    #pragma unroll
    for (int tc = 0; tc < 4; ++tc) cst[tc] = (f32x4_t){0.f, 0.f, 0.f, 0.f};

    auto lstm_step = [&](uint32_t xpack) {
        const uint8_t* hrow = hb + c * HROW_BYTES;
        bf16x8_t a0 = *(const bf16x8_t*)(hrow + q * 16);
        bf16x8_t a1 = *(const bf16x8_t*)(hrow + 64 + q * 16);
        union { bf16x8_t v; uint32_t u[4]; } ua;
        ua.u[0] = (q == 0) ? xpack : 0u;
        ua.u[1] = (q == 0) ? 0x00003F80u : 0u;   // bf16 1.0 at k=2
        ua.u[2] = 0u; ua.u[3] = 0u;
        bf16x8_t a2 = ua.v;

        #pragma unroll
        for (int tc = 0; tc < 4; ++tc) {
            f32x4_t acc[4];   // gi: 0=i,1=f,2=g,3=o  (tile = tc + 4*gi)
            #pragma unroll
            for (int gi = 0; gi < 4; ++gi) {
                int t = tc + gi * 4;
                bf16x8_t b0 = *(const bf16x8_t*)(sFrag + (2 * t) * 1024 + lane * 16);
                bf16x8_t b1 = *(const bf16x8_t*)(sFrag + (2 * t + 1) * 1024 + lane * 16);
                uint2 w2 = *(const uint2*)(sB2 + t * 512 + lane * 8);
                union { bf16x8_t v; uint32_t u[4]; } ub;
                ub.u[0] = w2.x; ub.u[1] = w2.y;
                ub.u[2] = 0u;   ub.u[3] = 0u;
                f32x4_t z = {0.f, 0.f, 0.f, 0.f};
                f32x4_t a = __builtin_amdgcn_mfma_f32_16x16x32_bf16(a0, b0, z, 0, 0, 0);
                a = __builtin_amdgcn_mfma_f32_16x16x32_bf16(a1, b1, a, 0, 0, 0);
                acc[gi] = __builtin_amdgcn_mfma_f32_16x16x32_bf16(a2, ub.v, a, 0, 0, 0);
            }
            float ec[4], ogs[4];
            #pragma unroll
            for (int r = 0; r < 4; ++r) {
                float ea  = __expf(-acc[0][r]);
                float efv = __expf(-acc[1][r]);
                float egv = __expf(-2.f * acc[2][r]);
                float eov = __expf(-acc[3][r]);
                float pa = 1.f + ea, pfv = 1.f + efv, pg = 1.f + egv, po = 1.f + eov;
                float A  = pa * pg, Bq = pfv * po;
                float rr = rcp_f(A * Bq);
                float rA = rr * A;                 // = 1/(pf*po)
                float igp = (1.f - egv) * rr * Bq; // = i*g
                float fgt = rA * po;               // = sigmoid(f)
                float ogt = rA * pfv;              // = sigmoid(o)
                float cn  = fgt * cst[tc][r] + igp;
                cst[tc][r] = cn;
                float cc = fminf(fmaxf(cn, -15.f), 15.f);
                ec[r]  = __expf(-2.f * cc);
                ogs[r] = ogt;
            }
            #pragma unroll
            for (int rp = 0; rp < 2; ++rp) {
                float e0 = ec[2 * rp], e1 = ec[2 * rp + 1];
                float C0 = 1.f + e0, C1 = 1.f + e1;
                float rr2 = rcp_f(C0 * C1);
                hst[tc][2 * rp]     = ogs[2 * rp]     * (1.f - e0) * rr2 * C1;
                hst[tc][2 * rp + 1] = ogs[2 * rp + 1] * (1.f - e1) * rr2 * C0;
            }
        }
        #pragma unroll
        for (int r = 0; r < 4; ++r) {
            uint2 u;
            u.x = pk((__bf16)hst[0][r], (__bf16)hst[1][r]);
            u.y = pk((__bf16)hst[2][r], (__bf16)hst[3][r]);
            *(uint2*)(hb + (4 * q + r) * HROW_BYTES + c * 8) = u;
        }
    };

    // ================= encoder =================
    const float* gsrc = in_seq + (size_t)(rowBase + (lane >> 2)) * (T_IN * 2)
                               + (lane & 3) * 8;
    float4 pf0 = *(const float4*)gsrc;
    float4 pf1 = *(const float4*)(gsrc + 4);

    #pragma unroll 1
    for (int t = 0; t < T_IN; ++t) {
        if ((t & 15) == 0) {
            int row = lane >> 2, s0 = (lane & 3) * 4;
            *(float2*)(sXw + (s0 + 0) * 128 + row * 8) = make_float2(pf0.x, pf0.y);
            *(float2*)(sXw + (s0 + 1) * 128 + row * 8) = make_float2(pf0.z, pf0.w);
            *(float2*)(sXw + (s0 + 2) * 128 + row * 8) = make_float2(pf1.x, pf1.y);
            *(float2*)(sXw + (s0 + 3) * 128 + row * 8) = make_float2(pf1.z, pf1.w);
            if (t < T_IN - 16) {
                const float* p = gsrc + ((t >> 4) + 1) * 32;
                pf0 = *(const float4*)p;
                pf1 = *(const float4*)(p + 4);
            }
        }
        float2 xv = *(const float2*)(sXw + (t & 15) * 128 + c * 8);
        lstm_step(pk((__bf16)xv.x, (__bf16)xv.y));
    }

    // ============ switch to decoder weights ============
    __syncthreads();
    stage_frags(WhhD, WihD, bihD, bhhD);
    __syncthreads();

    float wf0[4], wf1[4];
    #pragma unroll
    for (int tc = 0; tc < 4; ++tc) {
        wf0[tc] = Wfc[c + 16 * tc];
        wf1[tc] = Wfc[64 + c + 16 * tc];
    }
    const float bfc0 = bfc[0], bfc1 = bfc[1];

    float2 x127 = *(const float2*)(sXw + 15 * 128 + c * 8);   // input_seq[:, -1]
    uint32_t xpack = pk((__bf16)x127.x, (__bf16)x127.y);

    // ================= decoder =================
    #pragma unroll 1
    for (int td = 0; td < T_OUT; ++td) {
        lstm_step(xpack);
        float s0[4], s1[4];
        #pragma unroll
        for (int r = 0; r < 4; ++r) {
            s0[r] = hst[0][r]*wf0[0] + hst[1][r]*wf0[1] + hst[2][r]*wf0[2] + hst[3][r]*wf0[3];
            s1[r] = hst[0][r]*wf1[0] + hst[1][r]*wf1[1] + hst[2][r]*wf1[2] + hst[3][r]*wf1[3];
        }
        #pragma unroll
        for (int m = 1; m <= 8; m <<= 1) {
            #pragma unroll
            for (int r = 0; r < 4; ++r) {
                s0[r] += __shfl_xor(s0[r], m, 64);
                s1[r] += __shfl_xor(s1[r], m, 64);
            }
        }
        float x0n[4], x1n[4];
        #pragma unroll
        for (int r = 0; r < 4; ++r) {
            x0n[r] = rcp_f(1.f + __expf(-(s0[r] + bfc0)));
            x1n[r] = rcp_f(1.f + __expf(-(s1[r] + bfc1)));
        }
        if (c == 0) {
            #pragma unroll
            for (int r = 0; r < 4; ++r) {
                *(float2*)(out + ((size_t)(rowBase + 4 * q + r) * T_OUT + td) * 2)
                    = make_float2(x0n[r], x1n[r]);
            }
        }
        // route x(row c) to this lane: after the butterfly, lane (c>>2)*16
        // holds row c's value in register index (c&3)
        float t0[4], t1[4];
        #pragma unroll
        for (int r = 0; r < 4; ++r) {
            t0[r] = __shfl(x0n[r], (c >> 2) << 4, 64);
            t1[r] = __shfl(x1n[r], (c >> 2) << 4, 64);
        }
        float xa = (c & 2) ? ((c & 1) ? t0[3] : t0[2]) : ((c & 1) ? t0[1] : t0[0]);
        float xb = (c & 2) ? ((c & 1) ? t1[3] : t1[2]) : ((c & 1) ? t1[1] : t1[0]);
        xpack = pk((__bf16)xa, (__bf16)xb);
    }
}

extern "C" void kernel_launch(void* const* d_in, const int* in_sizes, int n_in,
                              void* d_out, int out_size, void* d_ws, size_t ws_size,
                              hipStream_t stream) {
    const float* in_seq = (const float*)d_in[0];
    const float* WihE = (const float*)d_in[1];
    const float* WhhE = (const float*)d_in[2];
    const float* bihE = (const float*)d_in[3];
    const float* bhhE = (const float*)d_in[4];
    const float* WihD = (const float*)d_in[5];
    const float* WhhD = (const float*)d_in[6];
    const float* bihD = (const float*)d_in[7];
    const float* bhhD = (const float*)d_in[8];
    const float* Wfc  = (const float*)d_in[9];
    const float* bfcp = (const float*)d_in[10];
    float* out = (float*)d_out;

    const int B = in_sizes[0] / (T_IN * 2);   // 131072
    dim3 grid(B / (NW * 16)), block(NW * 64); // 64 rows/block (4 waves x 16)
    hipLaunchKernelGGL(seq2seq_lstm, grid, block, 0, stream,
                       in_seq, WihE, WhhE, bihE, bhhE,
                       WihD, WhhD, bihD, bhhD, Wfc, bfcp, out);
}